// Round 2
// baseline (171.968 us; speedup 1.0000x reference)
//
#include <hip/hip_runtime.h>
#include <stdint.h>

typedef _Float16 f16;
typedef f16 f16x8 __attribute__((ext_vector_type(8)));
typedef float f32x4 __attribute__((ext_vector_type(4)));

#define NUM_NODES 20000
#define NUM_EDGES 65536
#define WIDTH 64
#define EDGE_FEAT 6
#define HIDDEN 128
#define BM 256            // edges per workgroup
#define NCHUNK 129        // 128 h-chunks + 1 bias chunk (h==1)
#define XPAD 72           // x-tile row stride in halfs (144B = 9*16, breaks bank conflicts)

#define XH_HALFS (NUM_NODES * WIDTH)   // 1,280,000 halfs for x in f16
#define XCONV_BLKS 625                 // 625 * 2048 halfs = 1,280,000 exactly

// ---------------------------------------------------------------------------
// Prep: (a) build W2g: 129 chunks of [64n x 64k] f16, transposed + XOR-granule
//       swizzled so main-kernel B-fragment ds_read_b128 is conflict-free.
//       chunk ki<128: B[k][n] = W2[ki][k*64+n]; chunk 128: B[k][n]=b2[k*64+n]
//       physical half index within chunk: n*64 + ((k>>3) ^ (n&7))*8 + (k&7)
//       (b) convert x to f16.
// ---------------------------------------------------------------------------
__global__ __launch_bounds__(256) void prep_kernel(
    const float* __restrict__ x, const float* __restrict__ W2,
    const float* __restrict__ b2, f16* __restrict__ ws_h)
{
  __shared__ float row[4096];
  f16* x_h = ws_h;
  f16* W2g = ws_h + XH_HALFS;
  const int blk = blockIdx.x, tid = threadIdx.x;

  if (blk < NCHUNK) {
    const int ki = blk;
    const float* srcrow;
    if (ki < HIDDEN) {
      const float4* src = (const float4*)(W2 + (size_t)ki * 4096);
      #pragma unroll
      for (int i = 0; i < 4; ++i) {
        float4 v = src[tid + 256 * i];
        *(float4*)&row[(tid + 256 * i) * 4] = v;
      }
      __syncthreads();
      srcrow = row;
    } else {
      srcrow = b2;  // bias chunk, read straight from global
    }
    const int obase = tid * 16;
    f16x8 outv0, outv1;
    #pragma unroll
    for (int u = 0; u < 8; ++u) {
      int o = obase + u;
      int n = o >> 6, pg = (o >> 3) & 7, j = o & 7;
      int k = (pg ^ (n & 7)) * 8 + j;
      outv0[u] = (f16)srcrow[k * 64 + n];
    }
    #pragma unroll
    for (int u = 0; u < 8; ++u) {
      int o = obase + 8 + u;
      int n = o >> 6, pg = (o >> 3) & 7, j = o & 7;
      int k = (pg ^ (n & 7)) * 8 + j;
      outv1[u] = (f16)srcrow[k * 64 + n];
    }
    *(f16x8*)&W2g[(size_t)ki * 4096 + obase] = outv0;
    *(f16x8*)&W2g[(size_t)ki * 4096 + obase + 8] = outv1;
  } else {
    // x fp32 -> f16
    int idx = (blk - NCHUNK) * 2048 + tid * 8;
    if (idx + 8 <= XH_HALFS) {
      float4 a = *(const float4*)(x + idx);
      float4 b = *(const float4*)(x + idx + 4);
      f16x8 hv;
      hv[0] = (f16)a.x; hv[1] = (f16)a.y; hv[2] = (f16)a.z; hv[3] = (f16)a.w;
      hv[4] = (f16)b.x; hv[5] = (f16)b.y; hv[6] = (f16)b.z; hv[7] = (f16)b.w;
      *(f16x8*)&x_h[idx] = hv;
    }
  }
}

// ---------------------------------------------------------------------------
// Main fused kernel: per WG, 256 edges x 64 outputs.
//   A[e, ki*64+w] = h[e,ki] * x[s_e, w]  (generated in registers)
//   B = W2g chunks (LDS double-buffered, 8KB/chunk)
//   h recomputed per ki from edge_attr registers (6 FMAs per row)
//   epilogue: atomicAdd scatter to out[receivers[e]]
// ---------------------------------------------------------------------------
__global__ __launch_bounds__(256, 1) void nnconv_kernel(
    const float* __restrict__ ea, const float* __restrict__ W1,
    const float* __restrict__ b1, const int* __restrict__ senders,
    const int* __restrict__ receivers, const f16* __restrict__ ws_h,
    float* __restrict__ out)
{
  const f16* x_h = ws_h;
  const f16* W2g = ws_h + XH_HALFS;
  __shared__ __align__(16) f16 xt[BM][XPAD];     // 36 KB
  __shared__ __align__(16) f16 Bb[2][4096];      // 16 KB

  const int tid = threadIdx.x;
  const int lane = tid & 63, wid = tid >> 6;
  const int quad = lane >> 4, l15 = lane & 15;
  const int e0 = blockIdx.x * BM;
  const int rowbase = wid * 64;

  // ---- gather sender x rows (f16) into LDS: 1 thread per row, 128B each
  {
    int s = senders[e0 + tid];
    const uint4* src = (const uint4*)(x_h + (size_t)s * WIDTH);
    uint4* dst = (uint4*)&xt[tid][0];
    #pragma unroll
    for (int i = 0; i < 8; ++i) dst[i] = src[i];
  }

  // ---- per-lane edge_attr rows (for h recompute): rows rowbase + t*16 + l15
  float ear[4][6];
  #pragma unroll
  for (int t = 0; t < 4; ++t) {
    const float* p = ea + (size_t)(e0 + rowbase + t * 16 + l15) * EDGE_FEAT;
    #pragma unroll
    for (int f = 0; f < 6; ++f) ear[t][f] = p[f];
  }

  // ---- per-lane B-fragment LDS offsets (swizzled), invariant across ki
  int boff[2][4];
  #pragma unroll
  for (int kc = 0; kc < 2; ++kc)
    #pragma unroll
    for (int nt = 0; nt < 4; ++nt) {
      int n = nt * 16 + l15;
      int g = kc * 4 + quad;
      boff[kc][nt] = n * 64 + (g ^ (n & 7)) * 8;
    }

  // ---- prefetch B chunk 0 into registers
  uint4 pre0 = *(const uint4*)(W2g + (size_t)tid * 16);
  uint4 pre1 = *(const uint4*)(W2g + (size_t)tid * 16 + 8);

  __syncthreads();  // xt ready

  // ---- x fragments (A-layout: m = l15, k-octet = quad), held all loop
  f16x8 xf[4][2];
  #pragma unroll
  for (int t = 0; t < 4; ++t)
    #pragma unroll
    for (int kc = 0; kc < 2; ++kc)
      xf[t][kc] = *(const f16x8*)&xt[rowbase + t * 16 + l15][kc * 32 + quad * 8];

  f32x4 acc[4][4];
  #pragma unroll
  for (int t = 0; t < 4; ++t)
    #pragma unroll
    for (int nt = 0; nt < 4; ++nt)
      acc[t][nt] = (f32x4){0.f, 0.f, 0.f, 0.f};

  for (int ki = 0; ki < NCHUNK; ++ki) {
    f16* buf = &Bb[ki & 1][0];
    *(uint4*)&buf[tid * 16] = pre0;
    *(uint4*)&buf[tid * 16 + 8] = pre1;
    if (ki + 1 < NCHUNK) {
      pre0 = *(const uint4*)(W2g + (size_t)(ki + 1) * 4096 + tid * 16);
      pre1 = *(const uint4*)(W2g + (size_t)(ki + 1) * 4096 + tid * 16 + 8);
    }

    // h values for this ki (4 rows per lane); wave-uniform W1 column loads
    f16 hv[4];
    if (ki < HIDDEN) {
      float b1c = b1[ki];
      float w1c[6];
      #pragma unroll
      for (int f = 0; f < 6; ++f) w1c[f] = W1[f * HIDDEN + ki];
      #pragma unroll
      for (int t = 0; t < 4; ++t) {
        float s = b1c;
        #pragma unroll
        for (int f = 0; f < 6; ++f) s = fmaf(ear[t][f], w1c[f], s);
        hv[t] = (f16)fmaxf(s, 0.f);
      }
    } else {
      #pragma unroll
      for (int t = 0; t < 4; ++t) hv[t] = (f16)1.f;  // bias chunk
    }

    __syncthreads();  // staging of buf complete (all threads)

    // B fragments (conflict-free via swizzle)
    f16x8 bf[2][4];
    #pragma unroll
    for (int kc = 0; kc < 2; ++kc)
      #pragma unroll
      for (int nt = 0; nt < 4; ++nt)
        bf[kc][nt] = *(const f16x8*)&buf[boff[kc][nt]];

    #pragma unroll
    for (int t = 0; t < 4; ++t) {
      f16x8 sa0 = xf[t][0] * hv[t];   // v_pk_mul_f16 x4
      f16x8 sa1 = xf[t][1] * hv[t];
      #pragma unroll
      for (int nt = 0; nt < 4; ++nt) {
        acc[t][nt] = __builtin_amdgcn_mfma_f32_16x16x32_f16(sa0, bf[0][nt], acc[t][nt], 0, 0, 0);
        acc[t][nt] = __builtin_amdgcn_mfma_f32_16x16x32_f16(sa1, bf[1][nt], acc[t][nt], 0, 0, 0);
      }
    }
  }

  // ---- epilogue: C-layout row = quad*4 + reg, col = l15; scatter-add
  #pragma unroll
  for (int t = 0; t < 4; ++t) {
    int ebase = e0 + rowbase + t * 16 + quad * 4;
    int rc[4];
    #pragma unroll
    for (int r = 0; r < 4; ++r) rc[r] = receivers[ebase + r];
    #pragma unroll
    for (int nt = 0; nt < 4; ++nt) {
      int v = nt * 16 + l15;
      #pragma unroll
      for (int r = 0; r < 4; ++r)
        atomicAdd(out + (size_t)rc[r] * WIDTH + v, acc[t][nt][r]);
    }
  }
}

extern "C" void kernel_launch(void* const* d_in, const int* in_sizes, int n_in,
                              void* d_out, int out_size, void* d_ws, size_t ws_size,
                              hipStream_t stream) {
  const float* x  = (const float*)d_in[0];
  const float* ea = (const float*)d_in[1];
  const float* W1 = (const float*)d_in[2];
  const float* b1 = (const float*)d_in[3];
  const float* W2 = (const float*)d_in[4];
  const float* b2 = (const float*)d_in[5];
  const int* snd  = (const int*)d_in[6];
  const int* rcv  = (const int*)d_in[7];
  float* out = (float*)d_out;
  f16* wsh = (f16*)d_ws;

  hipMemsetAsync(d_out, 0, (size_t)out_size * sizeof(float), stream);
  prep_kernel<<<NCHUNK + XCONV_BLKS, 256, 0, stream>>>(x, W2, b2, wsh);
  nnconv_kernel<<<NUM_EDGES / BM, 256, 0, stream>>>(ea, W1, b1, snd, rcv, wsh, out);
}

// Round 3
// 149.649 us; speedup vs baseline: 1.1491x; 1.1491x over previous
//
#include <hip/hip_runtime.h>
#include <stdint.h>

typedef _Float16 f16;
typedef f16 f16x8 __attribute__((ext_vector_type(8)));
typedef float f32x4 __attribute__((ext_vector_type(4)));

#define NUM_NODES 20000
#define NUM_EDGES 65536
#define WIDTH 64
#define EDGE_FEAT 6
#define HIDDEN 128
#define BM 256            // edges per workgroup
#define NCHUNK 129        // 128 h-chunks + 1 bias chunk (h==1)
#define XPAD 72           // x-tile row stride in halfs

#define XH_HALFS (NUM_NODES * WIDTH)   // 1,280,000 halfs for x in f16
#define XCONV_BLKS 625                 // 625 * 2048 halfs = 1,280,000 exactly

// ---------------------------------------------------------------------------
// Prep: (a) build W2g: 129 chunks of [64n x 64k] f16, transposed + XOR-granule
//       swizzled so main-kernel B-fragment ds_read_b128 is conflict-free.
//       physical half index within chunk: n*64 + ((k>>3) ^ (n&7))*8 + (k&7)
//       (b) convert x to f16.
// ---------------------------------------------------------------------------
__global__ __launch_bounds__(256) void prep_kernel(
    const float* __restrict__ x, const float* __restrict__ W2,
    const float* __restrict__ b2, f16* __restrict__ ws_h)
{
  __shared__ float row[4096];
  f16* x_h = ws_h;
  f16* W2g = ws_h + XH_HALFS;
  const int blk = blockIdx.x, tid = threadIdx.x;

  if (blk < NCHUNK) {
    const int ki = blk;
    const float* srcrow;
    if (ki < HIDDEN) {
      const float4* src = (const float4*)(W2 + (size_t)ki * 4096);
      #pragma unroll
      for (int i = 0; i < 4; ++i) {
        float4 v = src[tid + 256 * i];
        *(float4*)&row[(tid + 256 * i) * 4] = v;
      }
      __syncthreads();
      srcrow = row;
    } else {
      srcrow = b2;  // bias chunk, read straight from global
    }
    const int obase = tid * 16;
    f16x8 outv0, outv1;
    #pragma unroll
    for (int u = 0; u < 8; ++u) {
      int o = obase + u;
      int n = o >> 6, pg = (o >> 3) & 7, j = o & 7;
      int k = (pg ^ (n & 7)) * 8 + j;
      outv0[u] = (f16)srcrow[k * 64 + n];
    }
    #pragma unroll
    for (int u = 0; u < 8; ++u) {
      int o = obase + 8 + u;
      int n = o >> 6, pg = (o >> 3) & 7, j = o & 7;
      int k = (pg ^ (n & 7)) * 8 + j;
      outv1[u] = (f16)srcrow[k * 64 + n];
    }
    *(f16x8*)&W2g[(size_t)ki * 4096 + obase] = outv0;
    *(f16x8*)&W2g[(size_t)ki * 4096 + obase + 8] = outv1;
  } else {
    // x fp32 -> f16
    int idx = (blk - NCHUNK) * 2048 + tid * 8;
    if (idx + 8 <= XH_HALFS) {
      float4 a = *(const float4*)(x + idx);
      float4 b = *(const float4*)(x + idx + 4);
      f16x8 hv;
      hv[0] = (f16)a.x; hv[1] = (f16)a.y; hv[2] = (f16)a.z; hv[3] = (f16)a.w;
      hv[4] = (f16)b.x; hv[5] = (f16)b.y; hv[6] = (f16)b.z; hv[7] = (f16)b.w;
      *(f16x8*)&x_h[idx] = hv;
    }
  }
}

// ---------------------------------------------------------------------------
// Main fused kernel, K-split x2: grid 512.
//   blockIdx & 255  -> edge chunk (256 edges)
//   blockIdx >> 8   -> k-half: ki in [0,65) or [65,129)
// Per WG: A[e, ki*64+w] = h[e,ki] * x[s_e, w] generated in registers;
// B chunks (8KB) double-buffered in LDS via conflict-free identity staging;
// partial sums scatter-added to out (both halves atomicAdd).
// ---------------------------------------------------------------------------
__global__ __launch_bounds__(256, 2) void nnconv_kernel(
    const float* __restrict__ ea, const float* __restrict__ W1,
    const float* __restrict__ b1, const int* __restrict__ senders,
    const int* __restrict__ receivers, const f16* __restrict__ ws_h,
    float* __restrict__ out)
{
  const f16* x_h = ws_h;
  const f16* W2g = ws_h + XH_HALFS;
  __shared__ __align__(16) f16 xt[BM][XPAD];     // 36 KB
  __shared__ __align__(16) f16 Bb[2][4096];      // 16 KB

  const int tid = threadIdx.x;
  const int lane = tid & 63, wid = tid >> 6;
  const int quad = lane >> 4, l15 = lane & 15;
  const int chunk = blockIdx.x & 255;
  const int khalf = blockIdx.x >> 8;
  const int k0 = khalf ? 65 : 0;
  const int kcount = khalf ? 64 : 65;
  const int e0 = chunk * BM;
  const int rowbase = wid * 64;

  // ---- gather sender x rows (f16) into LDS: 1 thread per row, 128B each
  {
    int s = senders[e0 + tid];
    const uint4* src = (const uint4*)(x_h + (size_t)s * WIDTH);
    uint4* dst = (uint4*)&xt[tid][0];
    #pragma unroll
    for (int i = 0; i < 8; ++i) dst[i] = src[i];
  }

  // ---- per-lane edge_attr rows (for h recompute): rows rowbase + t*16 + l15
  float ear[4][6];
  #pragma unroll
  for (int t = 0; t < 4; ++t) {
    const float* p = ea + (size_t)(e0 + rowbase + t * 16 + l15) * EDGE_FEAT;
    #pragma unroll
    for (int f = 0; f < 6; ++f) ear[t][f] = p[f];
  }

  // ---- per-lane B-fragment LDS offsets (swizzled), invariant across ki
  int boff[2][4];
  #pragma unroll
  for (int kc = 0; kc < 2; ++kc)
    #pragma unroll
    for (int nt = 0; nt < 4; ++nt) {
      int n = nt * 16 + l15;
      int g = kc * 4 + quad;
      boff[kc][nt] = n * 64 + (g ^ (n & 7)) * 8;
    }

  // ---- prefetch B chunk k0 (identity-copy layout: 16B per thread per half)
  uint4 pre0 = *(const uint4*)(W2g + (size_t)k0 * 4096 + tid * 8);
  uint4 pre1 = *(const uint4*)(W2g + (size_t)k0 * 4096 + 2048 + tid * 8);

  __syncthreads();  // xt ready

  // ---- x fragments (A-layout: m = l15, k-octet = quad), held all loop
  f16x8 xf[4][2];
  #pragma unroll
  for (int t = 0; t < 4; ++t)
    #pragma unroll
    for (int kc = 0; kc < 2; ++kc)
      xf[t][kc] = *(const f16x8*)&xt[rowbase + t * 16 + l15][kc * 32 + quad * 8];

  f32x4 acc[4][4];
  #pragma unroll
  for (int t = 0; t < 4; ++t)
    #pragma unroll
    for (int nt = 0; nt < 4; ++nt)
      acc[t][nt] = (f32x4){0.f, 0.f, 0.f, 0.f};

  for (int kk = 0; kk < kcount; ++kk) {
    const int ki = k0 + kk;
    f16* buf = &Bb[kk & 1][0];
    // conflict-free staging: lane writes 16B at byte 16*tid in each 4KB half
    *(uint4*)&buf[tid * 8] = pre0;
    *(uint4*)&buf[2048 + tid * 8] = pre1;
    if (kk + 1 < kcount) {
      pre0 = *(const uint4*)(W2g + (size_t)(ki + 1) * 4096 + tid * 8);
      pre1 = *(const uint4*)(W2g + (size_t)(ki + 1) * 4096 + 2048 + tid * 8);
    }

    // h values for this ki (4 rows per lane); wave-uniform W1 column loads
    f16 hv[4];
    if (ki < HIDDEN) {
      float b1c = b1[ki];
      float w1c[6];
      #pragma unroll
      for (int f = 0; f < 6; ++f) w1c[f] = W1[f * HIDDEN + ki];
      #pragma unroll
      for (int t = 0; t < 4; ++t) {
        float s = b1c;
        #pragma unroll
        for (int f = 0; f < 6; ++f) s = fmaf(ear[t][f], w1c[f], s);
        hv[t] = (f16)fmaxf(s, 0.f);
      }
    } else {
      #pragma unroll
      for (int t = 0; t < 4; ++t) hv[t] = (f16)1.f;  // bias chunk
    }

    __syncthreads();  // staging of buf complete (all threads)

    // B fragments (conflict-free via swizzle)
    f16x8 bf[2][4];
    #pragma unroll
    for (int kc = 0; kc < 2; ++kc)
      #pragma unroll
      for (int nt = 0; nt < 4; ++nt)
        bf[kc][nt] = *(const f16x8*)&buf[boff[kc][nt]];

    #pragma unroll
    for (int t = 0; t < 4; ++t) {
      f16x8 sa0 = xf[t][0] * hv[t];   // v_pk_mul_f16 x4
      f16x8 sa1 = xf[t][1] * hv[t];
      #pragma unroll
      for (int nt = 0; nt < 4; ++nt) {
        acc[t][nt] = __builtin_amdgcn_mfma_f32_16x16x32_f16(sa0, bf[0][nt], acc[t][nt], 0, 0, 0);
        acc[t][nt] = __builtin_amdgcn_mfma_f32_16x16x32_f16(sa1, bf[1][nt], acc[t][nt], 0, 0, 0);
      }
    }
  }

  // ---- epilogue: C-layout row = quad*4 + reg, col = l15; scatter-add
  #pragma unroll
  for (int t = 0; t < 4; ++t) {
    int ebase = e0 + rowbase + t * 16 + quad * 4;
    int rc[4];
    #pragma unroll
    for (int r = 0; r < 4; ++r) rc[r] = receivers[ebase + r];
    #pragma unroll
    for (int nt = 0; nt < 4; ++nt) {
      int v = nt * 16 + l15;
      #pragma unroll
      for (int r = 0; r < 4; ++r)
        atomicAdd(out + (size_t)rc[r] * WIDTH + v, acc[t][nt][r]);
    }
  }
}

extern "C" void kernel_launch(void* const* d_in, const int* in_sizes, int n_in,
                              void* d_out, int out_size, void* d_ws, size_t ws_size,
                              hipStream_t stream) {
  const float* x  = (const float*)d_in[0];
  const float* ea = (const float*)d_in[1];
  const float* W1 = (const float*)d_in[2];
  const float* b1 = (const float*)d_in[3];
  const float* W2 = (const float*)d_in[4];
  const float* b2 = (const float*)d_in[5];
  const int* snd  = (const int*)d_in[6];
  const int* rcv  = (const int*)d_in[7];
  float* out = (float*)d_out;
  f16* wsh = (f16*)d_ws;

  hipMemsetAsync(d_out, 0, (size_t)out_size * sizeof(float), stream);
  prep_kernel<<<NCHUNK + XCONV_BLKS, 256, 0, stream>>>(x, W2, b2, wsh);
  nnconv_kernel<<<2 * (NUM_EDGES / BM), 256, 0, stream>>>(ea, W1, b1, snd, rcv, wsh, out);
}